// Round 4
// baseline (349.093 us; speedup 1.0000x reference)
//
#include <hip/hip_runtime.h>
#include <hip/hip_cooperative_groups.h>

namespace cg = cooperative_groups;

#define HALF   4096
#define NROWS  8192
#define DDIM   128
#define NGROUPS (NROWS / 128)                  // 64 row/col groups of 128
#define NPAIRS  (NGROUPS * (NGROUPS + 1) / 2)  // 2080 triangular tile-blocks
#define LDS_STRIDE 272                          // 256B row + 16B pad (conflict-free b128)
#define GRID   1024                             // 4 blocks/CU x 256 CU, co-resident

typedef _Float16 v8h __attribute__((ext_vector_type(8)));
typedef _Float16 v2h __attribute__((ext_vector_type(2)));
typedef float    v4f __attribute__((ext_vector_type(4)));

#if __has_builtin(__builtin_amdgcn_exp2f)
#define EXP2F(x) __builtin_amdgcn_exp2f(x)
#else
#define EXP2F(x) exp2f(x)
#endif
#if __has_builtin(__builtin_amdgcn_logf)
#define LOG2F(x) __builtin_amdgcn_logf(x)
#else
#define LOG2F(x) __log2f(x)
#endif

#define CEXP 2.8853900817779268f   // 2/ln2 : exp(2g-2) = 2^(CEXP*g - CEXP)

// R4: the R3 chain's ~40 us controllable share decomposes as ~8 us of kernel
// work (trans-pipe-limited gram ~5, normalize ~1.2, correct ~1.5) + ~30 us of
// dispatch overhead (3 launches x ~10 us, per rocprof.md; corroborated by
// R0->R1's -12 us for one dropped dispatch + small rework). So: ONE
// cooperative kernel, two grid.sync()s. Co-residency: LDS 36.9 KB -> 4
// blocks/CU; __launch_bounds__(256,4) caps VGPR for 16 waves/CU; grid 1024.
// R2 lesson stays honored: no scratch round-trips, S built by L2 atomics.

// ---------------- fused cooperative kernel ----------------
__global__ __launch_bounds__(256, 4) void nt_fused(
        const float* __restrict__ z_i, const float* __restrict__ z_j,
        _Float16* __restrict__ zn, float* __restrict__ S,
        float* __restrict__ P, float* __restrict__ out) {
    __shared__ unsigned char lds[128 * LDS_STRIDE];   // 34816 B
    __shared__ float cs[4][128];                      // col-sum combine
    __shared__ float red[4];

    int tid  = threadIdx.x;
    int lane = tid & 63;
    int w    = tid >> 6;       // wave 0..3
    int quad = lane >> 4;      // 0..3
    int cl   = lane & 15;      // 0..15
    int bid  = blockIdx.x;

    // ---- Phase 1: normalize 8 rows/block -> fp16; zero S (ws is poisoned) ----
    if (tid < 8) S[bid * 8 + tid] = 0.f;
    #pragma unroll
    for (int it = 0; it < 2; ++it) {
        int row = bid * 8 + it * 4 + w;
        const float* src = (row < HALF) ? (z_i + (size_t)row * DDIM)
                                        : (z_j + (size_t)(row - HALF) * DDIM);
        float2 v = *(const float2*)(src + lane * 2);
        float ss = v.x * v.x + v.y * v.y;
        #pragma unroll
        for (int off = 32; off >= 1; off >>= 1)
            ss += __shfl_xor(ss, off, 64);
        float inv = 1.0f / fmaxf(sqrtf(ss), 1e-8f);
        v2h pq;
        pq.x = (_Float16)(v.x * inv);
        pq.y = (_Float16)(v.y * inv);
        *(v2h*)(zn + (size_t)row * DDIM + lane * 2) = pq;
    }

    __threadfence();
    cg::this_grid().sync();

    // ---- Phase 2: triangular gram tiles; blocks 0..31 take 3 tiles, rest 2 ----
    for (int p = bid; p < NPAIRS; p += GRID) {
        __syncthreads();   // all waves done reading LDS from the previous tile

        // decode triangular pair index -> (I, J), I <= J
        int J = (int)((sqrtf(8.0f * (float)p + 1.0f) - 1.0f) * 0.5f);
        while ((J + 1) * (J + 2) / 2 <= p) ++J;
        while (J * (J + 1) / 2 > p) --J;
        int I = p - J * (J + 1) / 2;
        int r0 = I * 128, c0 = J * 128;
        bool offdiag = (I != J);
        bool ppart   = (J == I + 32);   // local diagonal = partner sims

        // A fragments: wave w owns 32 rows (2 tiles of 16), kept in registers.
        // A-operand layout: lane holds A[m = lane&15][k = quad*8 + j]
        v8h a[2][4];
        #pragma unroll
        for (int u = 0; u < 2; ++u) {
            int arow = r0 + w * 32 + u * 16 + cl;
            #pragma unroll
            for (int t = 0; t < 4; ++t)
                a[u][t] = *(const v8h*)(zn + (size_t)arow * DDIM + t * 32 + quad * 8);
        }

        // stage the 128-column tile (128 x 128 f16 = 32 KB), padded rows
        const uint4* gb = (const uint4*)zn;   // 1 uint4 = 8 f16
        #pragma unroll
        for (int i = 0; i < 8; ++i) {
            int rr = (tid >> 4) + i * 16;     // column index within tile
            uint4 v = gb[(size_t)(c0 + rr) * 16 + (tid & 15)];
            *(uint4*)&lds[(size_t)rr * LDS_STRIDE + (tid & 15) * 16] = v;
        }
        __syncthreads();

        float sums[2][4] = {{0.f,0.f,0.f,0.f},{0.f,0.f,0.f,0.f}};

        #pragma unroll
        for (int sub = 0; sub < 8; ++sub) {
            v4f acc0 = {0.f, 0.f, 0.f, 0.f};
            v4f acc1 = {0.f, 0.f, 0.f, 0.f};
            #pragma unroll
            for (int t = 0; t < 4; ++t) {
                v8h b = *(const v8h*)&lds[(size_t)(sub * 16 + cl) * LDS_STRIDE + t * 64 + quad * 16];
                acc0 = __builtin_amdgcn_mfma_f32_16x16x32_f16(a[0][t], b, acc0, 0, 0, 0);
                acc1 = __builtin_amdgcn_mfma_f32_16x16x32_f16(a[1][t], b, acc1, 0, 0, 0);
            }
            // epilogue: exp(2g-2); row sums in regs, column sums cross-lane.
            // C/D layout (16x16x32): col = lane&15, row = quad*4 + r.
            float cp = 0.f;
            #pragma unroll
            for (int r = 0; r < 4; ++r) {
                float e0 = EXP2F(fmaf(acc0[r], CEXP, -CEXP));
                float e1 = EXP2F(fmaf(acc1[r], CEXP, -CEXP));
                sums[0][r] += e0;
                sums[1][r] += e1;
                cp += e0 + e1;
                // partner-pair harvest: local row == local col  <=>
                // sub == w*2 + u  &&  cl == quad*4 + r  (sub unrolled-constant)
                if (ppart && cl == quad * 4 + r) {
                    if (sub == w * 2)     P[r0 + w * 32 +      quad * 4 + r] = e0;
                    if (sub == w * 2 + 1) P[r0 + w * 32 + 16 + quad * 4 + r] = e1;
                }
            }
            if (offdiag) {
                // column partials: reduce over the wave's 32 rows (across quads)
                cp += __shfl_xor(cp, 16, 64);
                cp += __shfl_xor(cp, 32, 64);
                if (quad == 0)
                    cs[w][sub * 16 + cl] = cp;
            }
        }

        // row sums: reduce across the 16 column-lanes, one atomic per row
        #pragma unroll
        for (int u = 0; u < 2; ++u)
            #pragma unroll
            for (int r = 0; r < 4; ++r) {
                float s = sums[u][r];
                #pragma unroll
                for (int off = 1; off < 16; off <<= 1)
                    s += __shfl_xor(s, off, 64);
                if (cl == 0)
                    atomicAdd(&S[r0 + w * 32 + u * 16 + quad * 4 + r], s);
            }

        // column sums: combine the 4 waves' partials, one atomic per column
        if (offdiag) {             // p is block-uniform -> barrier is safe
            __syncthreads();
            if (tid < 128) {
                float c = cs[0][tid] + cs[1][tid] + cs[2][tid] + cs[3][tid];
                atomicAdd(&S[c0 + tid], c);
            }
        }
    }

    __threadfence();
    cg::this_grid().sync();

    // ---- Phase 3: block 0 computes sum(log2(S - P)) and writes the loss ----
    if (bid == 0) {
        float part = 0.f;
        #pragma unroll
        for (int k = 0; k < 16; ++k) {
            int pr = k * 256 + tid;
            float e = P[pr];
            part += LOG2F(S[pr] - e) + LOG2F(S[pr + HALF] - e);
        }
        #pragma unroll
        for (int off = 32; off >= 1; off >>= 1)
            part += __shfl_xor(part, off, 64);
        if (lane == 0) red[w] = part;
        __syncthreads();
        if (tid == 0)
            out[0] = (red[0] + red[1] + red[2] + red[3])
                     * (0.69314718055994531f / (float)NROWS);
    }
}

// ---------------- fallback chain (R3 champion), used only if coop launch fails ----
__global__ __launch_bounds__(256) void nt_normalize(
        const float* __restrict__ z_i, const float* __restrict__ z_j,
        _Float16* __restrict__ zn, float* __restrict__ S) {
    int tid  = threadIdx.x;
    int lane = tid & 63;
    int row  = blockIdx.x * 4 + (tid >> 6);
    if (tid < 4) S[blockIdx.x * 4 + tid] = 0.f;
    const float* src = (row < HALF) ? (z_i + (size_t)row * DDIM)
                                    : (z_j + (size_t)(row - HALF) * DDIM);
    float2 v = *(const float2*)(src + lane * 2);
    float ss = v.x * v.x + v.y * v.y;
    #pragma unroll
    for (int off = 32; off >= 1; off >>= 1)
        ss += __shfl_xor(ss, off, 64);
    float inv = 1.0f / fmaxf(sqrtf(ss), 1e-8f);
    v2h p;
    p.x = (_Float16)(v.x * inv);
    p.y = (_Float16)(v.y * inv);
    *(v2h*)(zn + (size_t)row * DDIM + lane * 2) = p;
}

__global__ __launch_bounds__(256, 4) void nt_gram_sym(
        const _Float16* __restrict__ zn, float* __restrict__ S,
        float* __restrict__ P) {
    __shared__ unsigned char lds[128 * LDS_STRIDE];
    __shared__ float cs[4][128];
    int tid  = threadIdx.x;
    int lane = tid & 63;
    int w    = tid >> 6;
    int quad = lane >> 4;
    int cl   = lane & 15;
    int p = blockIdx.x;
    int J = (int)((sqrtf(8.0f * (float)p + 1.0f) - 1.0f) * 0.5f);
    while ((J + 1) * (J + 2) / 2 <= p) ++J;
    while (J * (J + 1) / 2 > p) --J;
    int I = p - J * (J + 1) / 2;
    int r0 = I * 128, c0 = J * 128;
    bool offdiag = (I != J);
    bool ppart   = (J == I + 32);
    v8h a[2][4];
    #pragma unroll
    for (int u = 0; u < 2; ++u) {
        int arow = r0 + w * 32 + u * 16 + cl;
        #pragma unroll
        for (int t = 0; t < 4; ++t)
            a[u][t] = *(const v8h*)(zn + (size_t)arow * DDIM + t * 32 + quad * 8);
    }
    const uint4* gb = (const uint4*)zn;
    #pragma unroll
    for (int i = 0; i < 8; ++i) {
        int rr = (tid >> 4) + i * 16;
        uint4 v = gb[(size_t)(c0 + rr) * 16 + (tid & 15)];
        *(uint4*)&lds[(size_t)rr * LDS_STRIDE + (tid & 15) * 16] = v;
    }
    __syncthreads();
    float sums[2][4] = {{0.f,0.f,0.f,0.f},{0.f,0.f,0.f,0.f}};
    #pragma unroll
    for (int sub = 0; sub < 8; ++sub) {
        v4f acc0 = {0.f, 0.f, 0.f, 0.f};
        v4f acc1 = {0.f, 0.f, 0.f, 0.f};
        #pragma unroll
        for (int t = 0; t < 4; ++t) {
            v8h b = *(const v8h*)&lds[(size_t)(sub * 16 + cl) * LDS_STRIDE + t * 64 + quad * 16];
            acc0 = __builtin_amdgcn_mfma_f32_16x16x32_f16(a[0][t], b, acc0, 0, 0, 0);
            acc1 = __builtin_amdgcn_mfma_f32_16x16x32_f16(a[1][t], b, acc1, 0, 0, 0);
        }
        float cp = 0.f;
        #pragma unroll
        for (int r = 0; r < 4; ++r) {
            float e0 = EXP2F(fmaf(acc0[r], CEXP, -CEXP));
            float e1 = EXP2F(fmaf(acc1[r], CEXP, -CEXP));
            sums[0][r] += e0;
            sums[1][r] += e1;
            cp += e0 + e1;
            if (ppart && cl == quad * 4 + r) {
                if (sub == w * 2)     P[r0 + w * 32 +      quad * 4 + r] = e0;
                if (sub == w * 2 + 1) P[r0 + w * 32 + 16 + quad * 4 + r] = e1;
            }
        }
        if (offdiag) {
            cp += __shfl_xor(cp, 16, 64);
            cp += __shfl_xor(cp, 32, 64);
            if (quad == 0)
                cs[w][sub * 16 + cl] = cp;
        }
    }
    #pragma unroll
    for (int u = 0; u < 2; ++u)
        #pragma unroll
        for (int r = 0; r < 4; ++r) {
            float s = sums[u][r];
            #pragma unroll
            for (int off = 1; off < 16; off <<= 1)
                s += __shfl_xor(s, off, 64);
            if (cl == 0)
                atomicAdd(&S[r0 + w * 32 + u * 16 + quad * 4 + r], s);
        }
    if (offdiag) {
        __syncthreads();
        if (tid < 128) {
            float c = cs[0][tid] + cs[1][tid] + cs[2][tid] + cs[3][tid];
            atomicAdd(&S[c0 + tid], c);
        }
    }
}

__global__ __launch_bounds__(1024) void nt_correct(
        const float* __restrict__ S, const float* __restrict__ P,
        float* __restrict__ out) {
    int tid = threadIdx.x;
    float part = 0.f;
    #pragma unroll
    for (int k = 0; k < 4; ++k) {
        int pr = tid + k * 1024;
        float e = P[pr];
        part += LOG2F(S[pr] - e) + LOG2F(S[pr + HALF] - e);
    }
    #pragma unroll
    for (int off = 32; off >= 1; off >>= 1)
        part += __shfl_xor(part, off, 64);
    __shared__ float red[16];
    if ((tid & 63) == 0) red[tid >> 6] = part;
    __syncthreads();
    if (tid == 0) {
        float t = 0.f;
        #pragma unroll
        for (int i = 0; i < 16; ++i) t += red[i];
        out[0] = t * (0.69314718055994531f / (float)NROWS);
    }
}

extern "C" void kernel_launch(void* const* d_in, const int* in_sizes, int n_in,
                              void* d_out, int out_size, void* d_ws, size_t ws_size,
                              hipStream_t stream) {
    const float* z_i = (const float*)d_in[0];
    const float* z_j = (const float*)d_in[1];
    _Float16* zn  = (_Float16*)d_ws;                                    // 2 MB
    float*    S   = (float*)((char*)d_ws + (size_t)NROWS * DDIM * 2);   // 8192 f32
    float*    P   = S + NROWS;                                          // 4096 f32
    float*    out = (float*)d_out;

    void* args[] = { (void*)&z_i, (void*)&z_j, (void*)&zn,
                     (void*)&S, (void*)&P, (void*)&out };
    hipError_t err = hipLaunchCooperativeKernel(
        (const void*)nt_fused, dim3(GRID), dim3(256), args, 0, stream);
    if (err != hipSuccess) {
        // fallback: R3 champion 3-kernel chain
        nt_normalize<<<dim3(NROWS / 4), dim3(256), 0, stream>>>(z_i, z_j, zn, S);
        nt_gram_sym<<<dim3(NPAIRS), dim3(256), 0, stream>>>(zn, S, P);
        nt_correct<<<dim3(1), dim3(1024), 0, stream>>>(S, P, out);
    }
}

// Round 5
// 82.836 us; speedup vs baseline: 4.2143x; 4.2143x over previous
//
#include <hip/hip_runtime.h>

#define HALF   4096
#define NROWS  8192
#define DDIM   128
#define NGROUPS (NROWS / 128)                  // 64 row/col groups of 128
#define NPAIRS  (NGROUPS * (NGROUPS + 1) / 2)  // 2080 triangular tile-blocks
#define LDS_STRIDE 272                          // 256B row + 16B pad (conflict-free b128)

typedef _Float16 v8h __attribute__((ext_vector_type(8)));
typedef _Float16 v2h __attribute__((ext_vector_type(2)));
typedef float    v4f __attribute__((ext_vector_type(4)));

#if __has_builtin(__builtin_amdgcn_exp2f)
#define EXP2F(x) __builtin_amdgcn_exp2f(x)
#else
#define EXP2F(x) exp2f(x)
#endif
#if __has_builtin(__builtin_amdgcn_logf)
#define LOG2F(x) __builtin_amdgcn_logf(x)
#else
#define LOG2F(x) __log2f(x)
#endif

#define CEXP 2.8853900817779268f   // 2/ln2 : exp(2g-2) = 2^(CEXP*g - CEXP)

// STRUCTURAL LEDGER (all harness-measured, this problem, this chip):
//   3-dispatch chain (this file)                          82.3 us  <- champion
//   R2: scratch round-trip replacing S atomics           +17.4 us
//   prior session: counter-gated single-address finalize  +9   us
//   R4: cooperative single-kernel, 2x grid.sync()       +266   us
//        (grid sync ~135 us EACH on gfx950 under graph capture;
//         occupancy 46% proved co-residency — it's the sync protocol,
//         not a spin-deadlock. MfmaUtil 1.2%, VALUBusy 2.9% during it.)
// Conclusion: dispatch gaps (~4-5 us) are the cheapest grid-wide barrier
// available. Do not re-attempt fusion without new evidence.

// ---------------- Kernel 1: row-normalize concat(z_i, z_j) -> fp16; zero S ----
__global__ __launch_bounds__(256) void nt_normalize(
        const float* __restrict__ z_i, const float* __restrict__ z_j,
        _Float16* __restrict__ zn, float* __restrict__ S) {
    int tid  = threadIdx.x;
    int lane = tid & 63;
    int row  = blockIdx.x * 4 + (tid >> 6);
    // zero the S accumulators nt_gram_sym atomicAdds into (ws is 0xAA-poisoned).
    // P needs no zero: every entry is plain-stored exactly once by gram.
    if (tid < 4) S[blockIdx.x * 4 + tid] = 0.f;

    const float* src = (row < HALF) ? (z_i + (size_t)row * DDIM)
                                    : (z_j + (size_t)(row - HALF) * DDIM);
    float2 v = *(const float2*)(src + lane * 2);
    float ss = v.x * v.x + v.y * v.y;
    #pragma unroll
    for (int off = 32; off >= 1; off >>= 1)
        ss += __shfl_xor(ss, off, 64);
    float inv = 1.0f / fmaxf(sqrtf(ss), 1e-8f);
    v2h p;
    p.x = (_Float16)(v.x * inv);
    p.y = (_Float16)(v.y * inv);
    *(v2h*)(zn + (size_t)row * DDIM + lane * 2) = p;
}

// ---------------- Kernel 2: symmetric Gram + shifted sum-exp, triangular tiles ----
// 2080 blocks = upper-triangle (I<=J) of the 64x64 grid of 128x128 tiles.
// 4 waves each own 32 rows (a[2][4] A-frags in regs) x all 128 cols; 8 subtiles.
// exp(sim) is symmetric: off-diagonal tiles scatter row-sums AND column-sums.
// Column-sum partials are combined across the 4 waves in LDS first ->
// 128 atomics/block instead of 512. Partner tiles (J == I+32) hold
// sim(r, r+HALF) on their local diagonal: the already-computed exp value is
// stored to P[r] with a predicated store (frees the tail from recomputing
// any dot products).
__global__ __launch_bounds__(256, 4) void nt_gram_sym(
        const _Float16* __restrict__ zn, float* __restrict__ S,
        float* __restrict__ P) {
    __shared__ unsigned char lds[128 * LDS_STRIDE];   // 34816 B
    __shared__ float cs[4][128];                      // +2048 B (col-sum combine)

    int tid  = threadIdx.x;
    int lane = tid & 63;
    int w    = tid >> 6;       // wave 0..3
    int quad = lane >> 4;      // 0..3
    int cl   = lane & 15;      // 0..15

    // decode triangular pair index -> (I, J), I <= J
    int p = blockIdx.x;
    int J = (int)((sqrtf(8.0f * (float)p + 1.0f) - 1.0f) * 0.5f);
    while ((J + 1) * (J + 2) / 2 <= p) ++J;
    while (J * (J + 1) / 2 > p) --J;
    int I = p - J * (J + 1) / 2;
    int r0 = I * 128, c0 = J * 128;
    bool offdiag = (I != J);
    bool ppart   = (J == I + 32);   // this tile's local diagonal = partner sims

    // A fragments: wave w owns 32 rows (2 tiles of 16), kept in registers.
    // A-operand layout: lane holds A[m = lane&15][k = quad*8 + j]
    v8h a[2][4];
    #pragma unroll
    for (int u = 0; u < 2; ++u) {
        int arow = r0 + w * 32 + u * 16 + cl;
        #pragma unroll
        for (int t = 0; t < 4; ++t)
            a[u][t] = *(const v8h*)(zn + (size_t)arow * DDIM + t * 32 + quad * 8);
    }

    // stage the 128-column tile (128 x 128 f16 = 32 KB) once, padded rows
    const uint4* gb = (const uint4*)zn;   // 1 uint4 = 8 f16
    #pragma unroll
    for (int i = 0; i < 8; ++i) {
        int rr = (tid >> 4) + i * 16;     // column index within tile
        uint4 v = gb[(size_t)(c0 + rr) * 16 + (tid & 15)];
        *(uint4*)&lds[(size_t)rr * LDS_STRIDE + (tid & 15) * 16] = v;
    }
    __syncthreads();

    float sums[2][4] = {{0.f,0.f,0.f,0.f},{0.f,0.f,0.f,0.f}};

    #pragma unroll
    for (int sub = 0; sub < 8; ++sub) {
        v4f acc0 = {0.f, 0.f, 0.f, 0.f};
        v4f acc1 = {0.f, 0.f, 0.f, 0.f};
        #pragma unroll
        for (int t = 0; t < 4; ++t) {
            v8h b = *(const v8h*)&lds[(size_t)(sub * 16 + cl) * LDS_STRIDE + t * 64 + quad * 16];
            acc0 = __builtin_amdgcn_mfma_f32_16x16x32_f16(a[0][t], b, acc0, 0, 0, 0);
            acc1 = __builtin_amdgcn_mfma_f32_16x16x32_f16(a[1][t], b, acc1, 0, 0, 0);
        }
        // epilogue: exp(2g-2); row sums in regs, column sums cross-lane.
        // C/D layout (16x16x32): col = lane&15, row = quad*4 + r.
        float cp = 0.f;
        #pragma unroll
        for (int r = 0; r < 4; ++r) {
            float e0 = EXP2F(fmaf(acc0[r], CEXP, -CEXP));
            float e1 = EXP2F(fmaf(acc1[r], CEXP, -CEXP));
            sums[0][r] += e0;
            sums[1][r] += e1;
            cp += e0 + e1;
            // partner-pair harvest: local row == local col  <=>
            // sub == w*2 + u  &&  cl == quad*4 + r  (sub is unrolled-constant)
            if (ppart && cl == quad * 4 + r) {
                if (sub == w * 2)     P[r0 + w * 32 +      quad * 4 + r] = e0;
                if (sub == w * 2 + 1) P[r0 + w * 32 + 16 + quad * 4 + r] = e1;
            }
        }
        if (offdiag) {
            // column partials: reduce over the wave's 32 rows (across quads),
            // park in LDS — cross-wave combine after the loop (1 atomic/col).
            cp += __shfl_xor(cp, 16, 64);
            cp += __shfl_xor(cp, 32, 64);
            if (quad == 0)
                cs[w][sub * 16 + cl] = cp;
        }
    }

    // row sums: reduce across the 16 column-lanes, one atomic per row
    #pragma unroll
    for (int u = 0; u < 2; ++u)
        #pragma unroll
        for (int r = 0; r < 4; ++r) {
            float s = sums[u][r];
            #pragma unroll
            for (int off = 1; off < 16; off <<= 1)
                s += __shfl_xor(s, off, 64);
            if (cl == 0)
                atomicAdd(&S[r0 + w * 32 + u * 16 + quad * 4 + r], s);
        }

    // column sums: combine the 4 waves' partials, one atomic per column
    if (offdiag) {                 // block-uniform -> barrier is safe
        __syncthreads();
        if (tid < 128) {
            float c = cs[0][tid] + cs[1][tid] + cs[2][tid] + cs[3][tid];
            atomicAdd(&S[c0 + tid], c);
        }
    }
}

// ---------------- Kernel 3: log(S - e_partner), reduce, scale — ONE block ----
// e_partner comes precomputed from the gram kernel's partner tiles via P.
// 4096 pairs / 1024 threads = 4 each: 12 coalesced loads + 8 log2 per thread,
// wave shfl-reduce, LDS combine, single store. No atomics, no extra dispatch.
__global__ __launch_bounds__(1024) void nt_correct(
        const float* __restrict__ S, const float* __restrict__ P,
        float* __restrict__ out) {
    int tid = threadIdx.x;
    float part = 0.f;
    #pragma unroll
    for (int k = 0; k < 4; ++k) {
        int pr = tid + k * 1024;
        float e = P[pr];
        part += LOG2F(S[pr] - e) + LOG2F(S[pr + HALF] - e);
    }
    #pragma unroll
    for (int off = 32; off >= 1; off >>= 1)
        part += __shfl_xor(part, off, 64);
    __shared__ float red[16];
    if ((tid & 63) == 0) red[tid >> 6] = part;
    __syncthreads();
    if (tid == 0) {
        float t = 0.f;
        #pragma unroll
        for (int i = 0; i < 16; ++i) t += red[i];
        out[0] = t * (0.69314718055994531f / (float)NROWS);
    }
}

extern "C" void kernel_launch(void* const* d_in, const int* in_sizes, int n_in,
                              void* d_out, int out_size, void* d_ws, size_t ws_size,
                              hipStream_t stream) {
    const float* z_i = (const float*)d_in[0];
    const float* z_j = (const float*)d_in[1];
    _Float16* zn  = (_Float16*)d_ws;                                    // 2 MB
    float*    S   = (float*)((char*)d_ws + (size_t)NROWS * DDIM * 2);   // 8192 f32
    float*    P   = S + NROWS;                                          // 4096 f32
    float*    out = (float*)d_out;

    nt_normalize<<<dim3(NROWS / 4), dim3(256), 0, stream>>>(z_i, z_j, zn, S);
    nt_gram_sym<<<dim3(NPAIRS), dim3(256), 0, stream>>>(zn, S, P);
    nt_correct<<<dim3(1), dim3(1024), 0, stream>>>(S, P, out);
}